// Round 2
// baseline (922.879 us; speedup 1.0000x reference)
//
#include <hip/hip_runtime.h>
#include <stdint.h>

// ---------------- problem constants ----------------
#define SDIM   128
#define SHY    7
#define SHX    14
#define CELLS  (SDIM*SDIM*SDIM)   // 2097152
#define COUT   64

// ---------------- scan geometry ----------------
#define SCAN_BLOCK 256
#define SCAN_ITEMS 8
#define SCAN_TILE  (SCAN_BLOCK*SCAN_ITEMS)   // 2048
#define NB1        (CELLS/SCAN_TILE)         // 1024

// ws layout (bytes):
//   g         : [0, CELLS*4)                 8 MB  float
//   mask      : [CELLS*4, CELLS*5)           2 MB  u8
//   blockSums : [CELLS*5, +4096)             u32[NB1]
//   total U   : [CELLS*5+4096, +4)           u32
//   cell_list : [CELLS*5+8192, +CELLS*4)     8 MB  u32
// total ~18.9 MB

// ---------------------------------------------------------------
__global__ void points_kernel(const int* __restrict__ idx,
                              const float* __restrict__ feat,
                              float* __restrict__ g,
                              unsigned char* __restrict__ mask, int n)
{
    int i = blockIdx.x * blockDim.x + threadIdx.x;
    if (i >= n) return;
    int x = idx[3*i+0], y = idx[3*i+1], z = idx[3*i+2];
    float f = feat[i];
    atomicAdd(&g[(x<<SHX)|(y<<SHY)|z], f);
    #pragma unroll
    for (int a = -1; a <= 1; ++a)
    #pragma unroll
    for (int b = -1; b <= 1; ++b)
    #pragma unroll
    for (int c = -1; c <= 1; ++c) {
        int nx = x+a, ny = y+b, nz = z+c;
        if ((unsigned)nx < SDIM && (unsigned)ny < SDIM && (unsigned)nz < SDIM)
            mask[(nx<<SHX)|(ny<<SHY)|nz] = 1;   // idempotent store, race-safe
    }
}

// ---------------------------------------------------------------
__global__ void scan1_kernel(const unsigned char* __restrict__ mask,
                             unsigned int* __restrict__ blockSums)
{
    __shared__ unsigned int lds[SCAN_BLOCK];
    int t = threadIdx.x;
    size_t base = (size_t)blockIdx.x * SCAN_TILE + (size_t)t * SCAN_ITEMS;
    unsigned long long v = *(const unsigned long long*)(mask + base);
    unsigned int s = (unsigned int)__popcll(v);  // bytes are 0/1
    lds[t] = s; __syncthreads();
    for (int off = SCAN_BLOCK/2; off > 0; off >>= 1) {
        if (t < off) lds[t] += lds[t+off];
        __syncthreads();
    }
    if (t == 0) blockSums[blockIdx.x] = lds[0];
}

// exclusive scan of NB1(=1024) block sums, single block of 1024 threads
__global__ void scan2_kernel(unsigned int* __restrict__ blockSums,
                             unsigned int* __restrict__ total)
{
    __shared__ unsigned int lds[NB1];
    int t = threadIdx.x;
    unsigned int v = blockSums[t];
    lds[t] = v; __syncthreads();
    for (int off = 1; off < NB1; off <<= 1) {
        unsigned int add = (t >= off) ? lds[t-off] : 0u;
        __syncthreads();
        lds[t] += add;
        __syncthreads();
    }
    blockSums[t] = lds[t] - v;          // exclusive
    if (t == NB1-1) *total = lds[t];    // total active count U
}

__global__ void scan3_kernel(const unsigned char* __restrict__ mask,
                             const unsigned int* __restrict__ blockOffs,
                             unsigned int* __restrict__ cell_list)
{
    __shared__ unsigned int lds[SCAN_BLOCK];
    int t = threadIdx.x;
    size_t base = (size_t)blockIdx.x * SCAN_TILE + (size_t)t * SCAN_ITEMS;
    unsigned long long v = *(const unsigned long long*)(mask + base);
    unsigned int cnt = (unsigned int)__popcll(v);
    lds[t] = cnt; __syncthreads();
    for (int off = 1; off < SCAN_BLOCK; off <<= 1) {
        unsigned int add = (t >= off) ? lds[t-off] : 0u;
        __syncthreads();
        lds[t] += add;
        __syncthreads();
    }
    unsigned int rank = blockOffs[blockIdx.x] + (lds[t] - cnt);
    #pragma unroll
    for (int k = 0; k < SCAN_ITEMS; ++k) {
        if ((v >> (8*k)) & 1ull)
            cell_list[rank++] = (unsigned int)(base + k);
    }
}

// ---------------------------------------------------------------
// uniq coords as float32. element-per-thread, fully coalesced.
__global__ void coords_kernel(const unsigned int* __restrict__ cell_list,
                              const unsigned int* __restrict__ totalp,
                              float* __restrict__ out, int rows)
{
    int e = blockIdx.x * blockDim.x + threadIdx.x;
    if (e >= 3*rows) return;
    unsigned int U = *totalp;
    int r = e / 3;
    int comp = e - 3*r;
    float val = 128.0f;
    if ((unsigned)r < U) {
        unsigned int cell = cell_list[r];
        unsigned int c = (comp == 0) ? (cell >> SHX)
                       : (comp == 1) ? ((cell >> SHY) & (SDIM-1))
                                     : (cell & (SDIM-1));
        val = (float)c;
    }
    out[e] = val;
}

// ---------------------------------------------------------------
// one wave per output row; lane = channel. grid-stride so the 27 weights
// live in VGPRs for the whole kernel. g-neighbor reads are wave-uniform.
__global__ __launch_bounds__(256)
void feat_kernel(const unsigned int* __restrict__ cell_list,
                 const unsigned int* __restrict__ totalp,
                 const float* __restrict__ g,
                 const float* __restrict__ w,   // [27][64]
                 float* __restrict__ out,       // [rows][64]
                 int rows)
{
    int lane  = threadIdx.x & 63;
    int wave  = (blockIdx.x * blockDim.x + threadIdx.x) >> 6;
    int nwav  = (gridDim.x * blockDim.x) >> 6;
    unsigned int U = *totalp;

    float wreg[27];
    #pragma unroll
    for (int t = 0; t < 27; ++t) wreg[t] = w[t*COUT + lane];

    for (int r = wave; r < rows; r += nwav) {
        float acc = 0.0f;
        if ((unsigned)r < U) {
            unsigned int cell = cell_list[r];
            cell = __builtin_amdgcn_readfirstlane(cell);   // wave-uniform
            int x = cell >> SHX, y = (cell >> SHY) & (SDIM-1), z = cell & (SDIM-1);
            #pragma unroll
            for (int t = 0; t < 27; ++t) {
                int a = t/9 - 1, b = (t/3)%3 - 1, c = t%3 - 1;
                int nx = x+a, ny = y+b, nz = z+c;
                float gv = 0.0f;
                if (((unsigned)nx < SDIM) & ((unsigned)ny < SDIM) & ((unsigned)nz < SDIM))
                    gv = g[(nx<<SHX)|(ny<<SHY)|nz];
                acc += wreg[t] * gv;
            }
        }
        out[(size_t)r * COUT + lane] = acc;
    }
}

// ---------------------------------------------------------------
extern "C" void kernel_launch(void* const* d_in, const int* in_sizes, int n_in,
                              void* d_out, int out_size, void* d_ws, size_t ws_size,
                              hipStream_t stream)
{
    const int*   indices  = (const int*)d_in[0];
    const float* features = (const float*)d_in[1];
    const float* weights  = (const float*)d_in[2];

    const int n    = in_sizes[1];          // features is (N,1)
    const int rows = out_size / (3 + COUT); // uniq rows = N*27

    float* out_coords = (float*)d_out;                      // [rows][3]
    float* out_feat   = out_coords + (size_t)3 * rows;      // [rows][64]

    char* ws = (char*)d_ws;
    float*          g         = (float*)ws;
    unsigned char*  mask      = (unsigned char*)(ws + (size_t)CELLS*4);
    unsigned int*   blockSums = (unsigned int*)(ws + (size_t)CELLS*5);
    unsigned int*   total     = (unsigned int*)(ws + (size_t)CELLS*5 + 4096);
    unsigned int*   cell_list = (unsigned int*)(ws + (size_t)CELLS*5 + 8192);

    // zero g (8MB) + mask (2MB) in one memset
    hipMemsetAsync(g, 0, (size_t)CELLS*5, stream);

    points_kernel<<<(n + 255)/256, 256, 0, stream>>>(indices, features, g, mask, n);
    scan1_kernel<<<NB1, SCAN_BLOCK, 0, stream>>>(mask, blockSums);
    scan2_kernel<<<1, NB1, 0, stream>>>(blockSums, total);
    scan3_kernel<<<NB1, SCAN_BLOCK, 0, stream>>>(mask, blockSums, cell_list);
    coords_kernel<<<(3*rows + 255)/256, 256, 0, stream>>>(cell_list, total, out_coords, rows);
    feat_kernel<<<2048, 256, 0, stream>>>(cell_list, total, g, weights, out_feat, rows);
}

// Round 3
// 470.487 us; speedup vs baseline: 1.9615x; 1.9615x over previous
//
#include <hip/hip_runtime.h>
#include <stdint.h>

// ---------------- problem constants ----------------
#define SDIM   128
#define SHY    7
#define SHX    14
#define CELLS  (SDIM*SDIM*SDIM)   // 2097152
#define COUT   64
#define NLINES (SDIM*SDIM)        // 16384 (x,y) z-lines
#define LINEW  136                // halo line: z=-1..134 (>=130 used, padded)

// ws layout (bytes):
//   g         : [0, CELLS*4)                 8 MB  float
//   mask      : [CELLS*4, CELLS*5)           2 MB  u8
//   line_cnt  : [CELLS*5, +64K)              u32[NLINES]
//   line_rank : [CELLS*5+64K, +64K)          u32[NLINES]
//   total U   : [CELLS*5+128K, +4)           u32

// ---------------------------------------------------------------
__global__ void points_kernel(const int* __restrict__ idx,
                              const float* __restrict__ feat,
                              float* __restrict__ g,
                              unsigned char* __restrict__ mask, int n)
{
    int i = blockIdx.x * blockDim.x + threadIdx.x;
    if (i >= n) return;
    int x = idx[3*i+0], y = idx[3*i+1], z = idx[3*i+2];
    float f = feat[i];
    atomicAdd(&g[(x<<SHX)|(y<<SHY)|z], f);
    #pragma unroll
    for (int a = -1; a <= 1; ++a)
    #pragma unroll
    for (int b = -1; b <= 1; ++b)
    #pragma unroll
    for (int c = -1; c <= 1; ++c) {
        int nx = x+a, ny = y+b, nz = z+c;
        if ((unsigned)nx < SDIM && (unsigned)ny < SDIM && (unsigned)nz < SDIM)
            mask[(nx<<SHX)|(ny<<SHY)|nz] = 1;   // idempotent store, race-safe
    }
}

// ---------------------------------------------------------------
// one thread per z-line: popcount its 128 mask bytes (each 0/1)
__global__ void line_count_kernel(const unsigned char* __restrict__ mask,
                                  unsigned int* __restrict__ cnt)
{
    int line = blockIdx.x * blockDim.x + threadIdx.x;   // 0..16383
    const uint4* p = (const uint4*)(mask + (size_t)line * SDIM);
    unsigned s = 0;
    #pragma unroll
    for (int k = 0; k < 8; ++k) {
        uint4 v = p[k];
        s += __popc(v.x) + __popc(v.y) + __popc(v.z) + __popc(v.w);
    }
    cnt[line] = s;
}

// exclusive scan of 16384 line counts; single block of 1024, 16 lines/thread
#define SCANT 1024
#define LPT   (NLINES/SCANT)   // 16
__global__ void line_scan_kernel(const unsigned int* __restrict__ cnt,
                                 unsigned int* __restrict__ rank,
                                 unsigned int* __restrict__ total)
{
    __shared__ unsigned int lds[SCANT];
    int t = threadIdx.x;
    unsigned int local[LPT];
    unsigned int s = 0;
    #pragma unroll
    for (int k = 0; k < LPT; ++k) { local[k] = cnt[t*LPT + k]; s += local[k]; }
    lds[t] = s; __syncthreads();
    for (int off = 1; off < SCANT; off <<= 1) {
        unsigned int add = (t >= off) ? lds[t-off] : 0u;
        __syncthreads();
        lds[t] += add;
        __syncthreads();
    }
    unsigned int run = lds[t] - s;      // exclusive prefix of this thread's chunk
    #pragma unroll
    for (int k = 0; k < LPT; ++k) { rank[t*LPT + k] = run; run += local[k]; }
    if (t == SCANT-1) *total = lds[t];
}

// ---------------------------------------------------------------
// one block per (x,y) line. Stage 9 neighbor z-lines of g in LDS, compute
// ranks via ballot prefix, then 4 waves x 32 cells x 64 channels with
// LDS-broadcast taps. Writes feat rows (contiguous ranks!) + coords.
__global__ __launch_bounds__(256)
void conv_line_kernel(const float* __restrict__ g,
                      const unsigned char* __restrict__ mask,
                      const unsigned int* __restrict__ line_rank,
                      const float* __restrict__ w,        // [27][64]
                      float* __restrict__ out_coords,     // [rows][3]
                      float* __restrict__ out_feat)       // [rows][64]
{
    __shared__ float gl[9][LINEW];
    __shared__ unsigned int rankz[SDIM];
    __shared__ unsigned int w0cnt;

    const int t   = threadIdx.x;
    const int bid = blockIdx.x;          // = x*128 + y
    const int x = bid >> 7, y = bid & 127;

    // ---- stage 9 halo lines (zero-filled at boundaries) ----
    for (int j = t; j < 9*LINEW; j += 256) {
        int l = j / LINEW, i = j - l*LINEW;
        int xx = x + (l/3) - 1, yy = y + (l%3) - 1, zz = i - 1;
        float v = 0.f;
        if ((unsigned)xx < SDIM && (unsigned)yy < SDIM && (unsigned)zz < SDIM)
            v = g[(xx<<SHX)|(yy<<SHY)|zz];
        gl[l][i] = v;
    }

    // ---- per-cell ranks: ballot prefix over the line's 128 mask bytes ----
    unsigned int pre = 0; int m = 0;
    if (t < SDIM) {
        m = mask[((size_t)bid << SHY) | t];
        unsigned long long b = __ballot(m != 0);
        int lane = t & 63;
        pre = __popcll(b & ((1ull << lane) - 1ull));
        if (t == 63) w0cnt = __popcll(b);
    }
    __syncthreads();                     // covers gl fill + w0cnt
    if (t < SDIM) {
        if (t >= 64) pre += w0cnt;
        rankz[t] = m ? (line_rank[bid] + pre) : 0xFFFFFFFFu;
    }
    __syncthreads();

    // ---- weights: lane = channel, 27 VGPRs ----
    const int lane = t & 63;
    float wreg[27];
    #pragma unroll
    for (int k = 0; k < 27; ++k) wreg[k] = w[k*COUT + lane];

    // ---- compute: wave handles 32 consecutive z ----
    const int zbase = (t >> 6) << 5;
    const float fx = (float)x, fy = (float)y;
    #pragma unroll
    for (int zi = 0; zi < 32; ++zi) {
        const int z = zbase + zi;
        float acc = 0.f;
        #pragma unroll
        for (int l = 0; l < 9; ++l) {
            // taps at halo idx z, z+1, z+2 (spatial z-1, z, z+1); CSE merges
            // the reads shared with neighboring zi in the unrolled body.
            acc += wreg[l*3+0] * gl[l][z]
                 + wreg[l*3+1] * gl[l][z+1]
                 + wreg[l*3+2] * gl[l][z+2];
        }
        unsigned int r = rankz[z];
        if (r != 0xFFFFFFFFu) {
            out_feat[(size_t)r*COUT + lane] = acc;
            if (lane < 3)
                out_coords[(size_t)r*3 + lane] = (lane==0) ? fx : ((lane==1) ? fy : (float)z);
        }
    }
}

// ---------------------------------------------------------------
// rows >= U: coords = 128.0, feat = 0. Grid-stride, float4 for feat.
__global__ void pad_kernel(const unsigned int* __restrict__ totalp,
                           float* __restrict__ out_coords,
                           float* __restrict__ out_feat, int rows)
{
    unsigned int U = *totalp;
    size_t gid  = (size_t)blockIdx.x * blockDim.x + threadIdx.x;
    size_t nthr = (size_t)gridDim.x * blockDim.x;

    float4* f4 = (float4*)out_feat;      // 16 float4 per row
    const float4 z4 = make_float4(0.f, 0.f, 0.f, 0.f);
    for (size_t i = (size_t)U*16 + gid; i < (size_t)rows*16; i += nthr) f4[i] = z4;

    for (size_t i = (size_t)U*3 + gid; i < (size_t)rows*3; i += nthr) out_coords[i] = 128.f;
}

// ---------------------------------------------------------------
extern "C" void kernel_launch(void* const* d_in, const int* in_sizes, int n_in,
                              void* d_out, int out_size, void* d_ws, size_t ws_size,
                              hipStream_t stream)
{
    const int*   indices  = (const int*)d_in[0];
    const float* features = (const float*)d_in[1];
    const float* weights  = (const float*)d_in[2];

    const int n    = in_sizes[1];             // features is (N,1)
    const int rows = out_size / (3 + COUT);   // uniq rows = N*27

    float* out_coords = (float*)d_out;                  // [rows][3]
    float* out_feat   = out_coords + (size_t)3 * rows;  // [rows][64]

    char* ws = (char*)d_ws;
    float*         g         = (float*)ws;
    unsigned char* mask      = (unsigned char*)(ws + (size_t)CELLS*4);
    unsigned int*  line_cnt  = (unsigned int*)(ws + (size_t)CELLS*5);
    unsigned int*  line_rank = (unsigned int*)(ws + (size_t)CELLS*5 + 65536);
    unsigned int*  total     = (unsigned int*)(ws + (size_t)CELLS*5 + 131072);

    hipMemsetAsync(g, 0, (size_t)CELLS*5, stream);   // zero g (8MB) + mask (2MB)

    points_kernel<<<(n + 255)/256, 256, 0, stream>>>(indices, features, g, mask, n);
    line_count_kernel<<<NLINES/256, 256, 0, stream>>>(mask, line_cnt);
    line_scan_kernel<<<1, SCANT, 0, stream>>>(line_cnt, line_rank, total);
    conv_line_kernel<<<NLINES, 256, 0, stream>>>(g, mask, line_rank, weights,
                                                 out_coords, out_feat);
    pad_kernel<<<1024, 256, 0, stream>>>(total, out_coords, out_feat, rows);
}